// Round 3
// baseline (865.113 us; speedup 1.0000x reference)
//
#include <hip/hip_runtime.h>

// DeepTreeLSTM on MI355X (gfx950). Handles inputs as EITHER fp32 or bf16 via a
// device-side dtype probe (flag in ws): bf16 N(0,1) shorts never have exponent
// field >= 0xC0; fp32 low-half shorts are uniform random (~25% do).
//
// Tree: 511 nodes, level d has 2^d nodes. h storage level-major:
//   base_d = 256*(2^d - 1)*256 elems, rows within level = b*2^d + j.
//
// Workspace (total ~119.0 MB, < 128e6):
//   h_all  bf16 [0,           66,977,792)
//   cbufA  bf16 [66,977,792, 100,532,224)   c for even levels (8,6,4,2,0)
//   cbufB  bf16 [100,532,224,117,309,440)   c for odd levels (7,5,3,1)
//   arena  bf16 [117,309,440,118,401,928)   converted weights/biases/emo
//   flag   int  [118,401,928,118,401,932)
//   x2     fp32 [118,401,936,118,958,992)

typedef __attribute__((ext_vector_type(8))) short short8;
typedef __attribute__((ext_vector_type(4))) float f32x4;

#define HB 256
#define BASE8 16711680   // 256*255*256

// arena element offsets
#define A_WIOU 0
#define A_UIOU 196608
#define A_BIOU 393216
#define A_UFW  393984
#define A_UFB  459520
#define A_WIN  459776
#define A_BIN  529408
#define A_WMID 529536
#define A_BMID 537728
#define A_WOUT 537792
#define A_BOUT 538048
#define A_EMO  538052
#define A_TOT  546244

__device__ __forceinline__ float b2f(short s){
  union { unsigned u; float f; } v; v.u = ((unsigned)(unsigned short)s) << 16; return v.f;
}
__device__ __forceinline__ short f2b(float f){
  union { float f; unsigned u; } v; v.f = f;
  unsigned r = v.u + 0x7fffu + ((v.u >> 16) & 1u);   // RNE
  return (short)(unsigned short)(r >> 16);
}
__device__ __forceinline__ float fsig(float x){ return 1.f / (1.f + __expf(-x)); }
__device__ __forceinline__ float ftanh(float x){
  x = fminf(fmaxf(x, -10.f), 10.f);
  float e = __expf(2.f * x);
  return (e - 1.f) / (e + 1.f);
}

// Load an 8-elem K-fragment from a logical tensor at element offset eoff.
__device__ __forceinline__ short8 ldfrag(const void* base, size_t eoff, bool isf){
  if (isf){
    const float* p = (const float*)base + eoff;
    const float4 u = *(const float4*)p;
    const float4 w = *(const float4*)(p + 4);
    short8 r;
    r[0]=f2b(u.x); r[1]=f2b(u.y); r[2]=f2b(u.z); r[3]=f2b(u.w);
    r[4]=f2b(w.x); r[5]=f2b(w.y); r[6]=f2b(w.z); r[7]=f2b(w.w);
    return r;
  }
  return *(const short8*)((const short*)base + eoff);
}

// ---------------- dtype probe: 1 block, writes flag (1 = fp32, 0 = bf16) -----------------
__global__ __launch_bounds__(256)
void probe_kernel(const void* __restrict__ X, int* __restrict__ flag)
{
  __shared__ int sh[256];
  const int t = threadIdx.x;
  const unsigned short* p = (const unsigned short*)X;
  int cnt = 0;
  #pragma unroll
  for (int k = 0; k < 16; ++k){
    unsigned e = (p[t * 16 + k] >> 7) & 0xFFu;
    cnt += (e >= 0xC0u);
  }
  sh[t] = cnt; __syncthreads();
  for (int s = 128; s > 0; s >>= 1){ if (t < s) sh[t] += sh[t + s]; __syncthreads(); }
  if (t == 0) *flag = (sh[0] >= 16) ? 1 : 0;
}

// ---------------- convert all small params into bf16 arena -------------------------------
__global__ __launch_bounds__(256)
void conv_kernel(const void* s0, const void* s1, const void* s2, const void* s3,
                 const void* s4, const void* s5, const void* s6, const void* s7,
                 const void* s8, const void* s9, const void* s10, const void* s11,
                 short* __restrict__ arena, const int* __restrict__ flag)
{
  const int i = blockIdx.x * 256 + threadIdx.x;
  if (i >= A_TOT) return;
  const int bounds[13] = {A_WIOU, A_UIOU, A_BIOU, A_UFW, A_UFB, A_WIN, A_BIN,
                          A_WMID, A_BMID, A_WOUT, A_BOUT, A_EMO, A_TOT};
  const void* sp[12] = {s0,s1,s2,s3,s4,s5,s6,s7,s8,s9,s10,s11};
  int seg = 0;
  #pragma unroll
  for (int k = 1; k < 12; ++k) if (i >= bounds[k]) seg = k;
  const int j = i - bounds[seg];
  const float v = (*flag) ? ((const float*)sp[seg])[j] : b2f(((const short*)sp[seg])[j]);
  arena[i] = f2b(v);
}

// ---------------- leaf: iou = X_leaf @ W_iou^T, fused gates (c_in = 0) -------------------
// grid (1024, 4), block 256. Wave: 32 rows x 32 gate-cols (x3 gates).
__global__ __launch_bounds__(256)
void leaf_kernel(const void* __restrict__ X, const short* __restrict__ arena,
                 const int* __restrict__ flag,
                 short* __restrict__ hall, short* __restrict__ cout)
{
  const bool isf = (*flag) != 0;
  const short* Wiou = arena + A_WIOU;
  const short* biou = arena + A_BIOU;
  const int lane = threadIdx.x & 63;
  const int w    = threadIdx.x >> 6;
  const int l15  = lane & 15;
  const int quad = lane >> 4;
  const int row0 = blockIdx.x * 64 + (w >> 1) * 32;
  const int gc0  = blockIdx.y * 64 + (w & 1) * 32;

  const int rA = row0 + l15;
  const int rB = rA + 16;
  const size_t offA = (size_t)((rA >> 8) * 511 + 255 + (rA & 255)) * HB + quad * 8;
  const size_t offB = (size_t)((rB >> 8) * 511 + 255 + (rB & 255)) * HB + quad * 8;

  const short* pb[3][2];
  #pragma unroll
  for (int g = 0; g < 3; ++g)
    #pragma unroll
    for (int t = 0; t < 2; ++t)
      pb[g][t] = Wiou + (size_t)(g * 256 + gc0 + t * 16 + l15) * HB + quad * 8;

  f32x4 acc[2][3][2];
  #pragma unroll
  for (int rt = 0; rt < 2; ++rt)
    #pragma unroll
    for (int g = 0; g < 3; ++g)
      #pragma unroll
      for (int t = 0; t < 2; ++t)
        acc[rt][g][t] = (f32x4){0.f, 0.f, 0.f, 0.f};

  for (int k = 0; k < HB; k += 32){
    short8 a0 = ldfrag(X, offA + k, isf);
    short8 a1 = ldfrag(X, offB + k, isf);
    #pragma unroll
    for (int g = 0; g < 3; ++g)
      #pragma unroll
      for (int t = 0; t < 2; ++t){
        short8 bfr = *(const short8*)(pb[g][t] + k);
        acc[0][g][t] = __builtin_amdgcn_mfma_f32_16x16x32_bf16(a0, bfr, acc[0][g][t], 0, 0, 0);
        acc[1][g][t] = __builtin_amdgcn_mfma_f32_16x16x32_bf16(a1, bfr, acc[1][g][t], 0, 0, 0);
      }
  }

  #pragma unroll
  for (int t = 0; t < 2; ++t){
    const int col = gc0 + t * 16 + l15;
    const float bi = b2f(biou[col]);
    const float bo = b2f(biou[256 + col]);
    const float bu = b2f(biou[512 + col]);
    #pragma unroll
    for (int rt = 0; rt < 2; ++rt){
      const int rbase = row0 + rt * 16 + quad * 4;
      const f32x4 vi = acc[rt][0][t];
      const f32x4 vo = acc[rt][1][t];
      const f32x4 vu = acc[rt][2][t];
      #pragma unroll
      for (int r = 0; r < 4; ++r){
        const int row = rbase + r;
        const float ig = fsig(vi[r] + bi);
        const float og = fsig(vo[r] + bo);
        const float ug = ftanh(vu[r] + bu);
        const float cv = ig * ug;                 // c input is zeros
        const float hv = og * ftanh(cv);
        const size_t o = (size_t)row * HB + col;
        hall[BASE8 + o] = f2b(hv);
        cout[o] = f2b(cv);
      }
    }
  }
}

// ---------------- per level: partial c_d = sum_k sigmoid(h_ch@Uf^T+bf)*c_ch --------------
// grid (Mc/64, 2), block 256. Writes partial parent c into cdst (iou adds i*u in place).
__global__ __launch_bounds__(256)
void fcagg_kernel(const short* __restrict__ hch, const short* __restrict__ cch,
                  const short* __restrict__ arena, short* __restrict__ cdst)
{
  const short* Ufw = arena + A_UFW;
  const short* Ufb = arena + A_UFB;
  const int lane = threadIdx.x & 63;
  const int w    = threadIdx.x >> 6;
  const int l15  = lane & 15;
  const int quad = lane >> 4;
  const int row0 = blockIdx.x * 64 + (w >> 1) * 32;
  const int col0 = blockIdx.y * 128 + (w & 1) * 64;

  const short* pa0 = hch + (size_t)(row0 + l15) * HB + quad * 8;
  const short* pa1 = pa0 + 16 * HB;
  const short* pb[4];
  #pragma unroll
  for (int t = 0; t < 4; ++t)
    pb[t] = Ufw + (size_t)(col0 + t * 16 + l15) * HB + quad * 8;

  f32x4 acc[2][4];
  #pragma unroll
  for (int rt = 0; rt < 2; ++rt)
    #pragma unroll
    for (int t = 0; t < 4; ++t)
      acc[rt][t] = (f32x4){0.f, 0.f, 0.f, 0.f};

  for (int k = 0; k < HB; k += 32){
    short8 a0 = *(const short8*)(pa0 + k);
    short8 a1 = *(const short8*)(pa1 + k);
    #pragma unroll
    for (int t = 0; t < 4; ++t){
      short8 bfr = *(const short8*)(pb[t] + k);
      acc[0][t] = __builtin_amdgcn_mfma_f32_16x16x32_bf16(a0, bfr, acc[0][t], 0, 0, 0);
      acc[1][t] = __builtin_amdgcn_mfma_f32_16x16x32_bf16(a1, bfr, acc[1][t], 0, 0, 0);
    }
  }

  #pragma unroll
  for (int t = 0; t < 4; ++t){
    const int col = col0 + t * 16 + l15;
    const float bf = b2f(Ufb[col]);
    #pragma unroll
    for (int rt = 0; rt < 2; ++rt){
      const int rbase = row0 + rt * 16 + quad * 4;   // even, multiple of 4
      const f32x4 d = acc[rt][t];
      const float c0 = b2f(cch[(size_t)(rbase + 0) * HB + col]);
      const float c1 = b2f(cch[(size_t)(rbase + 1) * HB + col]);
      const float c2 = b2f(cch[(size_t)(rbase + 2) * HB + col]);
      const float c3 = b2f(cch[(size_t)(rbase + 3) * HB + col]);
      const int p = rbase >> 1;
      cdst[(size_t)p * HB + col]       = f2b(fsig(d[0] + bf) * c0 + fsig(d[1] + bf) * c1);
      cdst[(size_t)(p + 1) * HB + col] = f2b(fsig(d[2] + bf) * c2 + fsig(d[3] + bf) * c3);
    }
  }
}

// ---------------- per level: iou = (h_2p + h_2p+1) @ U_iou^T, gates, c in-place ----------
// grid (Mp/64, 4), block 256.
__global__ __launch_bounds__(256)
void iou_kernel(const short* __restrict__ hch, const short* __restrict__ arena,
                short* __restrict__ cio, short* __restrict__ hout)
{
  const short* Uiou = arena + A_UIOU;
  const short* biou = arena + A_BIOU;
  const int lane = threadIdx.x & 63;
  const int w    = threadIdx.x >> 6;
  const int l15  = lane & 15;
  const int quad = lane >> 4;
  const int row0 = blockIdx.x * 64 + (w >> 1) * 32;
  const int gc0  = blockIdx.y * 64 + (w & 1) * 32;

  const int rA = row0 + l15;
  const short* pa00 = hch + (size_t)(2 * rA) * HB + quad * 8;
  const short* pa01 = pa00 + HB;
  const short* pa10 = hch + (size_t)(2 * (rA + 16)) * HB + quad * 8;
  const short* pa11 = pa10 + HB;

  const short* pb[3][2];
  #pragma unroll
  for (int g = 0; g < 3; ++g)
    #pragma unroll
    for (int t = 0; t < 2; ++t)
      pb[g][t] = Uiou + (size_t)(g * 256 + gc0 + t * 16 + l15) * HB + quad * 8;

  f32x4 acc[2][3][2];
  #pragma unroll
  for (int rt = 0; rt < 2; ++rt)
    #pragma unroll
    for (int g = 0; g < 3; ++g)
      #pragma unroll
      for (int t = 0; t < 2; ++t)
        acc[rt][g][t] = (f32x4){0.f, 0.f, 0.f, 0.f};

  for (int k = 0; k < HB; k += 32){
    short8 s00 = *(const short8*)(pa00 + k);
    short8 s01 = *(const short8*)(pa01 + k);
    short8 s10 = *(const short8*)(pa10 + k);
    short8 s11 = *(const short8*)(pa11 + k);
    short8 a0, a1;
    #pragma unroll
    for (int e = 0; e < 8; ++e){
      a0[e] = f2b(b2f(s00[e]) + b2f(s01[e]));
      a1[e] = f2b(b2f(s10[e]) + b2f(s11[e]));
    }
    #pragma unroll
    for (int g = 0; g < 3; ++g)
      #pragma unroll
      for (int t = 0; t < 2; ++t){
        short8 bfr = *(const short8*)(pb[g][t] + k);
        acc[0][g][t] = __builtin_amdgcn_mfma_f32_16x16x32_bf16(a0, bfr, acc[0][g][t], 0, 0, 0);
        acc[1][g][t] = __builtin_amdgcn_mfma_f32_16x16x32_bf16(a1, bfr, acc[1][g][t], 0, 0, 0);
      }
  }

  #pragma unroll
  for (int t = 0; t < 2; ++t){
    const int col = gc0 + t * 16 + l15;
    const float bi = b2f(biou[col]);
    const float bo = b2f(biou[256 + col]);
    const float bu = b2f(biou[512 + col]);
    #pragma unroll
    for (int rt = 0; rt < 2; ++rt){
      const int rbase = row0 + rt * 16 + quad * 4;
      const f32x4 vi = acc[rt][0][t];
      const f32x4 vo = acc[rt][1][t];
      const f32x4 vu = acc[rt][2][t];
      #pragma unroll
      for (int r = 0; r < 4; ++r){
        const int row = rbase + r;
        const size_t o = (size_t)row * HB + col;
        const float ci = b2f(cio[o]);               // partial c from fcagg
        const float ig = fsig(vi[r] + bi);
        const float og = fsig(vo[r] + bo);
        const float ug = ftanh(vu[r] + bu);
        const float cv = ig * ug + ci;
        const float hv = og * ftanh(cv);
        hout[o] = f2b(hv);
        cio[o]  = f2b(cv);
      }
    }
  }
}

// ---------------- final reduction: head_h, inner mean, emo -> x2 (fp32, B x 544) ----------
__global__ __launch_bounds__(256)
void reduce_kernel(const short* __restrict__ hall, const short* __restrict__ arena,
                   float* __restrict__ x2)
{
  const short* emo = arena + A_EMO;
  const int b = blockIdx.x, col = threadIdx.x;
  float sum = 0.f;
  size_t base = 0;
  for (int d = 0; d <= 8; ++d){
    const int m = 1 << d;
    const short* p = hall + base + (size_t)b * m * HB + col;
    for (int j = 0; j < m; ++j) sum += b2f(p[(size_t)j * HB]);
    base += (size_t)256 * m * HB;
  }
  const float head = b2f(hall[(size_t)b * HB + col]);
  const float last = b2f(hall[(size_t)BASE8 + ((size_t)b * 256 + 255) * HB + col]);
  const float inner = (sum - head - last) * (1.f / 509.f);
  x2[(size_t)b * 544 + col]       = head;
  x2[(size_t)b * 544 + 256 + col] = inner;
  if (col < 32) x2[(size_t)b * 544 + 512 + col] = b2f(emo[b * 32 + col]);
}

// ---------------- head MLP: 544 -> 128 -> 64 -> 4, one block per batch -------------------
__global__ __launch_bounds__(256)
void head_kernel(const float* __restrict__ x2, const short* __restrict__ arena,
                 const int* __restrict__ flag, void* __restrict__ outv)
{
  __shared__ float sx[544];
  __shared__ float sy1[128];
  __shared__ float sy2[64];
  const int b = blockIdx.x, t = threadIdx.x;
  for (int i = t; i < 544; i += 256) sx[i] = x2[(size_t)b * 544 + i];
  __syncthreads();
  if (t < 128){
    float a = b2f(arena[A_BIN + t]);
    const short* wr = arena + A_WIN + (size_t)t * 544;
    for (int k = 0; k < 544; ++k) a += sx[k] * b2f(wr[k]);
    sy1[t] = fmaxf(a, 0.f);
  }
  __syncthreads();
  if (t < 64){
    float a = b2f(arena[A_BMID + t]);
    const short* wr = arena + A_WMID + (size_t)t * 128;
    for (int k = 0; k < 128; ++k) a += sy1[k] * b2f(wr[k]);
    sy2[t] = fmaxf(a, 0.f);
  }
  __syncthreads();
  if (t < 4){
    float a = b2f(arena[A_BOUT + t]);
    const short* wr = arena + A_WOUT + (size_t)t * 64;
    for (int k = 0; k < 64; ++k) a += sy2[k] * b2f(wr[k]);
    const float sg = fsig(a);
    if (*flag) ((float*)outv)[(size_t)b * 4 + t] = sg;
    else       ((short*)outv)[(size_t)b * 4 + t] = f2b(sg);
  }
}

extern "C" void kernel_launch(void* const* d_in, const int* in_sizes, int n_in,
                              void* d_out, int out_size, void* d_ws, size_t ws_size,
                              hipStream_t stream)
{
  (void)in_sizes; (void)n_in; (void)out_size; (void)ws_size;
  const void* X    = d_in[0];
  // d_in[1] = h (zeros, unused), d_in[2] = c (zeros, unused)
  const void* emo  = d_in[3];
  const void* Wiou = d_in[4];
  const void* Uiou = d_in[5];
  const void* biou = d_in[6];
  const void* Ufw  = d_in[7];
  const void* Ufb  = d_in[8];
  const void* Win  = d_in[9];
  const void* bin  = d_in[10];
  const void* Wmid = d_in[11];
  const void* bmid = d_in[12];
  const void* Wout = d_in[13];
  const void* bout = d_in[14];

  char* ws = (char*)d_ws;
  short* h_all = (short*)ws;                    // 66,977,792 B
  short* cbufA = (short*)(ws + 66977792);       // 33,554,432 B (levels 8,6,4,2,0)
  short* cbufB = (short*)(ws + 100532224);      // 16,777,216 B (levels 7,5,3,1)
  short* arena = (short*)(ws + 117309440);      //  1,092,488 B
  int*   flag  = (int*)  (ws + 118401928);
  float* x2    = (float*)(ws + 118401936);      //    557,056 B -> ends 118,958,992

  dim3 blk(256);

  probe_kernel<<<dim3(1), blk, 0, stream>>>(X, flag);
  conv_kernel<<<dim3((A_TOT + 255) / 256), blk, 0, stream>>>(
      Wiou, Uiou, biou, Ufw, Ufb, Win, bin, Wmid, bmid, Wout, bout, emo, arena, flag);

  leaf_kernel<<<dim3(1024, 4), blk, 0, stream>>>(X, arena, flag, h_all, cbufA);

  for (int d = 7; d >= 0; --d){
    const int m = 1 << d;
    const size_t base_p  = (size_t)256 * (m - 1) * HB;
    const size_t base_ch = (size_t)256 * (2 * m - 1) * HB;
    short* csrc = ((d + 1) & 1) ? cbufB : cbufA;   // child level d+1
    short* cio  = (d & 1) ? cbufB : cbufA;         // this level d (partial then final)
    const int Mc = 256 * 2 * m;
    const int Mp = 256 * m;
    fcagg_kernel<<<dim3(Mc / 64, 2), blk, 0, stream>>>(h_all + base_ch, csrc, arena, cio);
    iou_kernel<<<dim3(Mp / 64, 4), blk, 0, stream>>>(h_all + base_ch, arena, cio,
                                                     h_all + base_p);
  }

  reduce_kernel<<<dim3(256), blk, 0, stream>>>(h_all, arena, x2);
  head_kernel<<<dim3(256), blk, 0, stream>>>(x2, arena, flag, d_out);
}

// Round 4
// 813.493 us; speedup vs baseline: 1.0635x; 1.0635x over previous
//
#include <hip/hip_runtime.h>

// DeepTreeLSTM on MI355X (gfx950). Inputs are fp32 (verified R3); device-side
// dtype probe kept for robustness. Tree: 511 nodes, level d has 2^d nodes.
// h storage level-major: base_d = 256*(2^d-1)*256 elems, row = b*2^d + j.
//
// Workspace:
//   h_all  bf16 [0,           66,977,792)
//   cbufA  bf16 [66,977,792, 100,532,224)   c for even levels (8,6,4,2,0)
//   cbufB  bf16 [100,532,224,117,309,440)   c for odd levels (7,5,3,1)
//   arena  bf16 [117,309,440,118,401,928)   converted weights/biases/emo
//   flag   int  [118,401,928,118,401,932)
//   x2     fp32 [118,401,936,118,958,992)
//   xleaf  bf16 [118,959,104,152,513,536)   cast leaf X (only if ws_size allows)

typedef __attribute__((ext_vector_type(8))) short short8;
typedef __attribute__((ext_vector_type(4))) float f32x4;

#define HB 256
#define BASE8 16711680   // 256*255*256

// arena element offsets
#define A_WIOU 0
#define A_UIOU 196608
#define A_BIOU 393216
#define A_UFW  393984
#define A_UFB  459520
#define A_WIN  459776
#define A_BIN  529408
#define A_WMID 529536
#define A_BMID 537728
#define A_WOUT 537792
#define A_BOUT 538048
#define A_EMO  538052
#define A_TOT  546244

__device__ __forceinline__ float b2f(short s){
  union { unsigned u; float f; } v; v.u = ((unsigned)(unsigned short)s) << 16; return v.f;
}
__device__ __forceinline__ short f2b(float f){
  union { float f; unsigned u; } v; v.f = f;
  unsigned r = v.u + 0x7fffu + ((v.u >> 16) & 1u);   // RNE
  return (short)(unsigned short)(r >> 16);
}
__device__ __forceinline__ float fsig(float x){ return 1.f / (1.f + __expf(-x)); }
__device__ __forceinline__ float ftanh(float x){
  x = fminf(fmaxf(x, -10.f), 10.f);
  float e = __expf(2.f * x);
  return (e - 1.f) / (e + 1.f);
}

__device__ __forceinline__ short8 ldfrag(const void* base, size_t eoff, bool isf){
  if (isf){
    const float* p = (const float*)base + eoff;
    const float4 u = *(const float4*)p;
    const float4 w = *(const float4*)(p + 4);
    short8 r;
    r[0]=f2b(u.x); r[1]=f2b(u.y); r[2]=f2b(u.z); r[3]=f2b(u.w);
    r[4]=f2b(w.x); r[5]=f2b(w.y); r[6]=f2b(w.z); r[7]=f2b(w.w);
    return r;
  }
  return *(const short8*)((const short*)base + eoff);
}

// ---------------- dtype probe: 1 block, writes flag (1 = fp32, 0 = bf16) -----------------
__global__ __launch_bounds__(256)
void probe_kernel(const void* __restrict__ X, int* __restrict__ flag)
{
  __shared__ int sh[256];
  const int t = threadIdx.x;
  const unsigned short* p = (const unsigned short*)X;
  int cnt = 0;
  #pragma unroll
  for (int k = 0; k < 16; ++k){
    unsigned e = (p[t * 16 + k] >> 7) & 0xFFu;
    cnt += (e >= 0xC0u);
  }
  sh[t] = cnt; __syncthreads();
  for (int s = 128; s > 0; s >>= 1){ if (t < s) sh[t] += sh[t + s]; __syncthreads(); }
  if (t == 0) *flag = (sh[0] >= 16) ? 1 : 0;
}

// ---------------- convert all small params into bf16 arena -------------------------------
__global__ __launch_bounds__(256)
void conv_kernel(const void* s0, const void* s1, const void* s2, const void* s3,
                 const void* s4, const void* s5, const void* s6, const void* s7,
                 const void* s8, const void* s9, const void* s10, const void* s11,
                 short* __restrict__ arena, const int* __restrict__ flag)
{
  const int i = blockIdx.x * 256 + threadIdx.x;
  if (i >= A_TOT) return;
  const int bounds[13] = {A_WIOU, A_UIOU, A_BIOU, A_UFW, A_UFB, A_WIN, A_BIN,
                          A_WMID, A_BMID, A_WOUT, A_BOUT, A_EMO, A_TOT};
  const void* sp[12] = {s0,s1,s2,s3,s4,s5,s6,s7,s8,s9,s10,s11};
  int seg = 0;
  #pragma unroll
  for (int k = 1; k < 12; ++k) if (i >= bounds[k]) seg = k;
  const int j = i - bounds[seg];
  const float v = (*flag) ? ((const float*)sp[seg])[j] : b2f(((const short*)sp[seg])[j]);
  arena[i] = f2b(v);
}

// ---------------- cast leaf X -> dense bf16 [65536 x 256] --------------------------------
__global__ __launch_bounds__(256)
void cast_kernel(const void* __restrict__ X, const int* __restrict__ flag,
                 short* __restrict__ xleaf)
{
  const int e0 = (blockIdx.x * 256 + threadIdx.x) * 8;
  const int r = e0 >> 8, col = e0 & 255;
  const size_t src = ((size_t)(r >> 8) * 511 + 255 + (r & 255)) * HB + col;
  short8 v;
  if (*flag){
    const float* p = (const float*)X + src;
    const float4 u = *(const float4*)p;
    const float4 w = *(const float4*)(p + 4);
    v[0]=f2b(u.x); v[1]=f2b(u.y); v[2]=f2b(u.z); v[3]=f2b(u.w);
    v[4]=f2b(w.x); v[5]=f2b(w.y); v[6]=f2b(w.z); v[7]=f2b(w.w);
  } else {
    v = *(const short8*)((const short*)X + src);
  }
  *(short8*)(xleaf + e0) = v;
}

// ---------------- leaf (fast): iou = xleaf @ W_iou^T, fused gates (c_in = 0) -------------
// grid (1024, 4), block 256. Wave: 32 rows x 32 gate-cols x 3 gates.
__global__ __launch_bounds__(256)
void leaf_fast(const short* __restrict__ xleaf, const short* __restrict__ arena,
               short* __restrict__ hall, short* __restrict__ cout)
{
  const short* Wiou = arena + A_WIOU;
  const short* biou = arena + A_BIOU;
  const int lane = threadIdx.x & 63;
  const int w    = threadIdx.x >> 6;
  const int l15  = lane & 15;
  const int quad = lane >> 4;
  const int row0 = blockIdx.x * 64 + (w >> 1) * 32;
  const int gc0  = blockIdx.y * 64 + (w & 1) * 32;

  const short* pa0 = xleaf + (size_t)(row0 + l15) * HB + quad * 8;
  const short* pa1 = pa0 + 16 * HB;

  const short* pb[3][2];
  #pragma unroll
  for (int g = 0; g < 3; ++g)
    #pragma unroll
    for (int t = 0; t < 2; ++t)
      pb[g][t] = Wiou + (size_t)(g * 256 + gc0 + t * 16 + l15) * HB + quad * 8;

  f32x4 acc[2][3][2];
  #pragma unroll
  for (int rt = 0; rt < 2; ++rt)
    #pragma unroll
    for (int g = 0; g < 3; ++g)
      #pragma unroll
      for (int t = 0; t < 2; ++t)
        acc[rt][g][t] = (f32x4){0.f, 0.f, 0.f, 0.f};

  #pragma unroll
  for (int k = 0; k < HB; k += 32){
    short8 a0 = *(const short8*)(pa0 + k);
    short8 a1 = *(const short8*)(pa1 + k);
    #pragma unroll
    for (int g = 0; g < 3; ++g)
      #pragma unroll
      for (int t = 0; t < 2; ++t){
        short8 bfr = *(const short8*)(pb[g][t] + k);
        acc[0][g][t] = __builtin_amdgcn_mfma_f32_16x16x32_bf16(a0, bfr, acc[0][g][t], 0, 0, 0);
        acc[1][g][t] = __builtin_amdgcn_mfma_f32_16x16x32_bf16(a1, bfr, acc[1][g][t], 0, 0, 0);
      }
  }

  #pragma unroll
  for (int t = 0; t < 2; ++t){
    const int col = gc0 + t * 16 + l15;
    const float bi = b2f(biou[col]);
    const float bo = b2f(biou[256 + col]);
    const float bu = b2f(biou[512 + col]);
    #pragma unroll
    for (int rt = 0; rt < 2; ++rt){
      const int rbase = row0 + rt * 16 + quad * 4;
      const f32x4 vi = acc[rt][0][t];
      const f32x4 vo = acc[rt][1][t];
      const f32x4 vu = acc[rt][2][t];
      #pragma unroll
      for (int r = 0; r < 4; ++r){
        const int row = rbase + r;
        const float ig = fsig(vi[r] + bi);
        const float og = fsig(vo[r] + bo);
        const float ug = ftanh(vu[r] + bu);
        const float cv = ig * ug;
        const float hv = og * ftanh(cv);
        const size_t o = (size_t)row * HB + col;
        hall[BASE8 + o] = f2b(hv);
        cout[o] = f2b(cv);
      }
    }
  }
}

// ---------------- leaf (fallback, dual-dtype, reads X in place) --------------------------
__global__ __launch_bounds__(256)
void leaf_any(const void* __restrict__ X, const short* __restrict__ arena,
              const int* __restrict__ flag,
              short* __restrict__ hall, short* __restrict__ cout)
{
  const bool isf = (*flag) != 0;
  const short* Wiou = arena + A_WIOU;
  const short* biou = arena + A_BIOU;
  const int lane = threadIdx.x & 63;
  const int w    = threadIdx.x >> 6;
  const int l15  = lane & 15;
  const int quad = lane >> 4;
  const int row0 = blockIdx.x * 64 + (w >> 1) * 32;
  const int gc0  = blockIdx.y * 64 + (w & 1) * 32;

  const int rA = row0 + l15;
  const int rB = rA + 16;
  const size_t offA = (size_t)((rA >> 8) * 511 + 255 + (rA & 255)) * HB + quad * 8;
  const size_t offB = (size_t)((rB >> 8) * 511 + 255 + (rB & 255)) * HB + quad * 8;

  const short* pb[3][2];
  #pragma unroll
  for (int g = 0; g < 3; ++g)
    #pragma unroll
    for (int t = 0; t < 2; ++t)
      pb[g][t] = Wiou + (size_t)(g * 256 + gc0 + t * 16 + l15) * HB + quad * 8;

  f32x4 acc[2][3][2];
  #pragma unroll
  for (int rt = 0; rt < 2; ++rt)
    #pragma unroll
    for (int g = 0; g < 3; ++g)
      #pragma unroll
      for (int t = 0; t < 2; ++t)
        acc[rt][g][t] = (f32x4){0.f, 0.f, 0.f, 0.f};

  for (int k = 0; k < HB; k += 32){
    short8 a0 = ldfrag(X, offA + k, isf);
    short8 a1 = ldfrag(X, offB + k, isf);
    #pragma unroll
    for (int g = 0; g < 3; ++g)
      #pragma unroll
      for (int t = 0; t < 2; ++t){
        short8 bfr = *(const short8*)(pb[g][t] + k);
        acc[0][g][t] = __builtin_amdgcn_mfma_f32_16x16x32_bf16(a0, bfr, acc[0][g][t], 0, 0, 0);
        acc[1][g][t] = __builtin_amdgcn_mfma_f32_16x16x32_bf16(a1, bfr, acc[1][g][t], 0, 0, 0);
      }
  }

  #pragma unroll
  for (int t = 0; t < 2; ++t){
    const int col = gc0 + t * 16 + l15;
    const float bi = b2f(biou[col]);
    const float bo = b2f(biou[256 + col]);
    const float bu = b2f(biou[512 + col]);
    #pragma unroll
    for (int rt = 0; rt < 2; ++rt){
      const int rbase = row0 + rt * 16 + quad * 4;
      const f32x4 vi = acc[rt][0][t];
      const f32x4 vo = acc[rt][1][t];
      const f32x4 vu = acc[rt][2][t];
      #pragma unroll
      for (int r = 0; r < 4; ++r){
        const int row = rbase + r;
        const float ig = fsig(vi[r] + bi);
        const float og = fsig(vo[r] + bo);
        const float ug = ftanh(vu[r] + bu);
        const float cv = ig * ug;
        const float hv = og * ftanh(cv);
        const size_t o = (size_t)row * HB + col;
        hall[BASE8 + o] = f2b(hv);
        cout[o] = f2b(cv);
      }
    }
  }
}

// ---------------- fused level kernel ------------------------------------------------------
// Block: 32 parents (=64 children) x 64 cols. Grid (Mp/32, 4).
// Phase 1: f-GEMM (64 children x 64 cols, K=256) -> c_agg into LDS (fp32).
// Phase 1.5: h_tild = h_2p + h_2p+1 -> LDS (bf16, padded stride 264).
// Phase 2: iou-GEMM (32 parents x 3 gates x 64 cols, A from LDS) -> gates -> h_p, c_p.
__global__ __launch_bounds__(256)
void level_kernel(const short* __restrict__ hch, const short* __restrict__ cch,
                  const short* __restrict__ arena,
                  short* __restrict__ hout, short* __restrict__ cdst)
{
  __shared__ float cagg[32][66];
  __shared__ __align__(16) short htld[32][264];

  const short* Ufw  = arena + A_UFW;
  const short* Ufb  = arena + A_UFB;
  const short* Uiou = arena + A_UIOU;
  const short* biou = arena + A_BIOU;

  const int lane = threadIdx.x & 63;
  const int w    = threadIdx.x >> 6;
  const int l15  = lane & 15;
  const int quad = lane >> 4;
  const int bx   = blockIdx.x;
  const int cb   = blockIdx.y * 64;

  // ---- Phase 1: f-GEMM. Wave w: child rows (w&1)*32 + 0..31, cols (w>>1)*32 + 0..31.
  {
    const int rlo = (w & 1) * 32;
    const int clo = (w >> 1) * 32;
    const short* pa0 = hch + (size_t)(64 * bx + rlo + l15) * HB + quad * 8;
    const short* pa1 = pa0 + 16 * HB;
    const short* pb0 = Ufw + (size_t)(cb + clo + l15) * HB + quad * 8;
    const short* pb1 = pb0 + 16 * HB;

    f32x4 acc[2][2];
    #pragma unroll
    for (int rt = 0; rt < 2; ++rt)
      #pragma unroll
      for (int t = 0; t < 2; ++t) acc[rt][t] = (f32x4){0.f,0.f,0.f,0.f};

    #pragma unroll
    for (int k = 0; k < HB; k += 32){
      short8 a0 = *(const short8*)(pa0 + k);
      short8 a1 = *(const short8*)(pa1 + k);
      short8 b0 = *(const short8*)(pb0 + k);
      short8 b1 = *(const short8*)(pb1 + k);
      acc[0][0] = __builtin_amdgcn_mfma_f32_16x16x32_bf16(a0, b0, acc[0][0], 0, 0, 0);
      acc[0][1] = __builtin_amdgcn_mfma_f32_16x16x32_bf16(a0, b1, acc[0][1], 0, 0, 0);
      acc[1][0] = __builtin_amdgcn_mfma_f32_16x16x32_bf16(a1, b0, acc[1][0], 0, 0, 0);
      acc[1][1] = __builtin_amdgcn_mfma_f32_16x16x32_bf16(a1, b1, acc[1][1], 0, 0, 0);
    }

    #pragma unroll
    for (int t = 0; t < 2; ++t){
      const int col_l = clo + t * 16 + l15;
      const float bf = b2f(Ufb[cb + col_l]);
      #pragma unroll
      for (int rt = 0; rt < 2; ++rt){
        const int rbase = rlo + rt * 16 + quad * 4;   // local child row, mult of 4
        const f32x4 d = acc[rt][t];
        const size_t crow = (size_t)(64 * bx + rbase) * HB + (cb + col_l);
        const float c0 = b2f(cch[crow]);
        const float c1 = b2f(cch[crow + HB]);
        const float c2 = b2f(cch[crow + 2 * HB]);
        const float c3 = b2f(cch[crow + 3 * HB]);
        const int p = rbase >> 1;
        cagg[p][col_l]     = fsig(d[0] + bf) * c0 + fsig(d[1] + bf) * c1;
        cagg[p + 1][col_l] = fsig(d[2] + bf) * c2 + fsig(d[3] + bf) * c3;
      }
    }
  }

  // ---- Phase 1.5: h_tild pair-sum into LDS. Thread t: parent t>>3, k-chunk (t&7)*32.
  {
    const int t = threadIdx.x;
    const int p = t >> 3;
    const int kb = (t & 7) * 32;
    const short* r0 = hch + (size_t)(64 * bx + 2 * p) * HB + kb;
    const short* r1 = r0 + HB;
    #pragma unroll
    for (int k2 = 0; k2 < 4; ++k2){
      short8 va = *(const short8*)(r0 + k2 * 8);
      short8 vb = *(const short8*)(r1 + k2 * 8);
      #pragma unroll
      for (int e = 0; e < 8; ++e)
        htld[p][kb + k2 * 8 + e] = f2b(b2f(va[e]) + b2f(vb[e]));
    }
  }

  __syncthreads();

  // ---- Phase 2: iou-GEMM. Wave w: parent rows (w&1)*16 + 0..15, cols (w>>1)*32 + 0..31.
  {
    const int rlo2 = (w & 1) * 16;
    const int clo2 = (w >> 1) * 32;

    const short* pb[3][2];
    #pragma unroll
    for (int g = 0; g < 3; ++g)
      #pragma unroll
      for (int t = 0; t < 2; ++t)
        pb[g][t] = Uiou + (size_t)(g * 256 + cb + clo2 + t * 16 + l15) * HB + quad * 8;

    f32x4 acc[3][2];
    #pragma unroll
    for (int g = 0; g < 3; ++g)
      #pragma unroll
      for (int t = 0; t < 2; ++t) acc[g][t] = (f32x4){0.f,0.f,0.f,0.f};

    #pragma unroll
    for (int k = 0; k < HB; k += 32){
      short8 a = *(const short8*)&htld[rlo2 + l15][quad * 8 + k];
      #pragma unroll
      for (int g = 0; g < 3; ++g)
        #pragma unroll
        for (int t = 0; t < 2; ++t){
          short8 bfr = *(const short8*)(pb[g][t] + k);
          acc[g][t] = __builtin_amdgcn_mfma_f32_16x16x32_bf16(a, bfr, acc[g][t], 0, 0, 0);
        }
    }

    #pragma unroll
    for (int t = 0; t < 2; ++t){
      const int col_l = clo2 + t * 16 + l15;
      const int gcol  = cb + col_l;
      const float bi = b2f(biou[gcol]);
      const float bo = b2f(biou[256 + gcol]);
      const float bu = b2f(biou[512 + gcol]);
      const f32x4 vi = acc[0][t];
      const f32x4 vo = acc[1][t];
      const f32x4 vu = acc[2][t];
      #pragma unroll
      for (int r = 0; r < 4; ++r){
        const int row_l = rlo2 + quad * 4 + r;        // local parent 0..31
        const float ci = cagg[row_l][col_l];
        const float ig = fsig(vi[r] + bi);
        const float og = fsig(vo[r] + bo);
        const float ug = ftanh(vu[r] + bu);
        const float cv = ig * ug + ci;
        const float hv = og * ftanh(cv);
        const size_t o = (size_t)(32 * bx + row_l) * HB + gcol;
        hout[o] = f2b(hv);
        cdst[o] = f2b(cv);
      }
    }
  }
}

// ---------------- final reduction: head_h, inner mean, emo -> x2 (fp32, B x 544) ----------
__global__ __launch_bounds__(1024)
void reduce_kernel(const short* __restrict__ hall, const short* __restrict__ arena,
                   float* __restrict__ x2)
{
  __shared__ float sums[32][256];
  const int b = blockIdx.x, t = threadIdx.x;
  const int g = t >> 5, cb = (t & 31) * 8;
  float s[8];
  #pragma unroll
  for (int e = 0; e < 8; ++e) s[e] = 0.f;
  size_t base = 0;
  for (int d = 0; d <= 8; ++d){
    const int m = 1 << d;
    for (int j = g; j < m; j += 32){
      const short8 v = *(const short8*)(hall + base + (size_t)(b * m + j) * HB + cb);
      #pragma unroll
      for (int e = 0; e < 8; ++e) s[e] += b2f(v[e]);
    }
    base += (size_t)256 * m * HB;
  }
  #pragma unroll
  for (int e = 0; e < 8; ++e) sums[g][cb + e] = s[e];
  __syncthreads();
  if (t < 256){
    float tot = 0.f;
    #pragma unroll
    for (int gg = 0; gg < 32; ++gg) tot += sums[gg][t];
    const float head = b2f(hall[(size_t)b * HB + t]);
    const float last = b2f(hall[(size_t)BASE8 + ((size_t)b * 256 + 255) * HB + t]);
    x2[(size_t)b * 544 + t]       = head;
    x2[(size_t)b * 544 + 256 + t] = (tot - head - last) * (1.f / 509.f);
  } else if (t < 288){
    x2[(size_t)b * 544 + 512 + (t - 256)] = b2f(arena[A_EMO + b * 32 + (t - 256)]);
  }
}

// ---------------- head MLP: 544 -> 128 -> 64 -> 4, one block per batch -------------------
__global__ __launch_bounds__(256)
void head_kernel(const float* __restrict__ x2, const short* __restrict__ arena,
                 const int* __restrict__ flag, void* __restrict__ outv)
{
  __shared__ float sx[544];
  __shared__ float sy1[128];
  __shared__ float sy2[64];
  const int b = blockIdx.x, t = threadIdx.x;
  for (int i = t; i < 544; i += 256) sx[i] = x2[(size_t)b * 544 + i];
  __syncthreads();
  if (t < 128){
    float a = b2f(arena[A_BIN + t]);
    const short* wr = arena + A_WIN + (size_t)t * 544;
    for (int k = 0; k < 544; ++k) a += sx[k] * b2f(wr[k]);
    sy1[t] = fmaxf(a, 0.f);
  }
  __syncthreads();
  if (t < 64){
    float a = b2f(arena[A_BMID + t]);
    const short* wr = arena + A_WMID + (size_t)t * 128;
    for (int k = 0; k < 128; ++k) a += sy1[k] * b2f(wr[k]);
    sy2[t] = fmaxf(a, 0.f);
  }
  __syncthreads();
  if (t < 4){
    float a = b2f(arena[A_BOUT + t]);
    const short* wr = arena + A_WOUT + (size_t)t * 64;
    for (int k = 0; k < 64; ++k) a += sy2[k] * b2f(wr[k]);
    const float sg = fsig(a);
    if (*flag) ((float*)outv)[(size_t)b * 4 + t] = sg;
    else       ((short*)outv)[(size_t)b * 4 + t] = f2b(sg);
  }
}

extern "C" void kernel_launch(void* const* d_in, const int* in_sizes, int n_in,
                              void* d_out, int out_size, void* d_ws, size_t ws_size,
                              hipStream_t stream)
{
  (void)in_sizes; (void)n_in; (void)out_size;
  const void* X    = d_in[0];
  const void* emo  = d_in[3];
  const void* Wiou = d_in[4];
  const void* Uiou = d_in[5];
  const void* biou = d_in[6];
  const void* Ufw  = d_in[7];
  const void* Ufb  = d_in[8];
  const void* Win  = d_in[9];
  const void* bin  = d_in[10];
  const void* Wmid = d_in[11];
  const void* bmid = d_in[12];
  const void* Wout = d_in[13];
  const void* bout = d_in[14];

  char* ws = (char*)d_ws;
  short* h_all = (short*)ws;
  short* cbufA = (short*)(ws + 66977792);
  short* cbufB = (short*)(ws + 100532224);
  short* arena = (short*)(ws + 117309440);
  int*   flag  = (int*)  (ws + 118401928);
  float* x2    = (float*)(ws + 118401936);
  short* xleaf = (short*)(ws + 118959104);
  const bool can_cast = ws_size >= 152513536u;

  dim3 blk(256);

  probe_kernel<<<dim3(1), blk, 0, stream>>>(X, flag);
  conv_kernel<<<dim3((A_TOT + 255) / 256), blk, 0, stream>>>(
      Wiou, Uiou, biou, Ufw, Ufb, Win, bin, Wmid, bmid, Wout, bout, emo, arena, flag);

  if (can_cast){
    cast_kernel<<<dim3(8192), blk, 0, stream>>>(X, flag, xleaf);
    leaf_fast<<<dim3(1024, 4), blk, 0, stream>>>(xleaf, arena, h_all, cbufA);
  } else {
    leaf_any<<<dim3(1024, 4), blk, 0, stream>>>(X, arena, flag, h_all, cbufA);
  }

  for (int d = 7; d >= 0; --d){
    const int m = 1 << d;
    const size_t base_p  = (size_t)256 * (m - 1) * HB;
    const size_t base_ch = (size_t)256 * (2 * m - 1) * HB;
    short* csrc = ((d + 1) & 1) ? cbufB : cbufA;
    short* cdst = (d & 1) ? cbufB : cbufA;
    const int Mp = 256 * m;
    level_kernel<<<dim3(Mp / 32, 4), blk, 0, stream>>>(h_all + base_ch, csrc, arena,
                                                       h_all + base_p, cdst);
  }

  reduce_kernel<<<dim3(256), dim3(1024), 0, stream>>>(h_all, arena, x2);
  head_kernel<<<dim3(256), blk, 0, stream>>>(x2, arena, flag, d_out);
}